// Round 8
// baseline (75.239 us; speedup 1.0000x reference)
//
#include <hip/hip_runtime.h>

#define HP 1.57079632679489662f

typedef float f32x4 __attribute__((ext_vector_type(4)));
typedef short sh4 __attribute__((ext_vector_type(4)));

__device__ __forceinline__ unsigned short f2bf(float f) {
  unsigned int u = __builtin_bit_cast(unsigned int, f);
  u += 0x7fffu + ((u >> 16) & 1u);
  return (unsigned short)(u >> 16);
}

// ---------------- helpers for 4x4 complex matrix absorption (G*M) ----------------
__device__ __forceinline__ void rowswap4(float (&mr)[4][4], float (&mi)[4][4], int a, int b) {
#pragma unroll
  for (int c = 0; c < 4; c++) {
    float tr = mr[a][c]; mr[a][c] = mr[b][c]; mr[b][c] = tr;
    float ti = mi[a][c]; mi[a][c] = mi[b][c]; mi[b][c] = ti;
  }
}

__device__ __forceinline__ void absorb_rz(float (&mr)[4][4], float (&mi)[4][4], float t, int bitpos) {
  float ch = cosf(0.5f * t), sh = sinf(0.5f * t);
#pragma unroll
  for (int r = 0; r < 4; r++) {
    float ph = ((r >> bitpos) & 1) ? sh : -sh;
#pragma unroll
    for (int c = 0; c < 4; c++) {
      float ar = mr[r][c], ai = mi[r][c];
      mr[r][c] = ch * ar - ph * ai;
      mi[r][c] = ch * ai + ph * ar;
    }
  }
}

__device__ __forceinline__ void absorb_ry(float (&mr)[4][4], float (&mi)[4][4], float t, int bitpos) {
  float ch = cosf(0.5f * t), sh = sinf(0.5f * t);
#pragma unroll
  for (int r = 0; r < 4; r++) {
    if ((r >> bitpos) & 1) continue;
    int rb = r | (1 << bitpos);
#pragma unroll
    for (int c = 0; c < 4; c++) {
      float ar = mr[r][c], ai = mi[r][c];
      float br = mr[rb][c], bi = mi[rb][c];
      mr[r][c]  = ch * ar - sh * br;  mi[r][c]  = ch * ai - sh * bi;
      mr[rb][c] = sh * ar + ch * br;  mi[rb][c] = sh * ai + ch * bi;
    }
  }
}

// ws layout:
//   int   meta[64]        @ 0    ; float Q1[8][8] @ 256 ; float E4[28][32] @ 512
//   bf16  Ub[8][512][32]  @ 4096 : chunk ks = k in [32ks,32ks+32); row m: 2r=Re,2r+1=Im
//         pair-packed: logical k = 32ks+16s+4lg+i lives at row-byte (slot p)*16 + 8s + 2i,
//         p = (lg + (m>>1)) & 3  (16B-slot rotation)

// ---------------- K0: edges (f64, exact numpy semantics) + gate fusion ----------------
__global__ __launch_bounds__(64) void prep_kernel(const float* __restrict__ wt,
                                                  const float* __restrict__ coup,
                                                  void* __restrict__ wsv) {
  const int lane = threadIdx.x;
  int* meta  = (int*)wsv;
  float* Q1  = (float*)((char*)wsv + 256);
  float* E4  = (float*)((char*)wsv + 512);

  double mn = 1e300, mx = -1e300;
  for (int k = 0; k < 64; k++) {
    double v = (double)coup[k];
    mn = v < mn ? v : mn;
    mx = v > mx ? v : mx;
  }
  int cnt = 0, myi = -1, myj = -1;
  for (int i = 0; i < 8; i++)
    for (int j = i + 1; j < 8; j++) {
      double cn = ((double)coup[i * 8 + j] - mn) / (mx - mn);
      if (cn > 0.5) {
        if (cnt == lane) { myi = i; myj = j; }
        cnt++;
      }
    }
  if (lane == 0) meta[0] = cnt;

  if (lane < 8) {
    float tx = wt[lane], ty = wt[8 + lane], tz = wt[16 + lane];
    float cx = cosf(0.5f * tx), sx = sinf(0.5f * tx);
    float cy = cosf(0.5f * ty), sy = sinf(0.5f * ty);
    float cz = cosf(0.5f * tz), sz = sinf(0.5f * tz);
    float m00r = cy * cx,  m00i = sy * sx;
    float m01r = -sy * cx, m01i = -cy * sx;
    float m10r = sy * cx,  m10i = -cy * sx;
    float m11r = cy * cx,  m11i = -sy * sx;
    float* q = Q1 + lane * 8;
    q[0] = cz * m00r + sz * m00i; q[1] = cz * m00i - sz * m00r;
    q[2] = cz * m01r + sz * m01i; q[3] = cz * m01i - sz * m01r;
    q[4] = cz * m10r - sz * m10i; q[5] = cz * m10i + sz * m10r;
    q[6] = cz * m11r - sz * m11i; q[7] = cz * m11i + sz * m11r;
  }

  if (lane < cnt && lane < 28) {
    float mr[4][4], mi[4][4];
#pragma unroll
    for (int r = 0; r < 4; r++)
#pragma unroll
      for (int c = 0; c < 4; c++) { mr[r][c] = (r == c) ? 1.f : 0.f; mi[r][c] = 0.f; }

    bool nonadj = (myj - myi) != 1;
    int wb = 24 + 6 * lane;

    if (nonadj) rowswap4(mr, mi, 1, 2);
    absorb_rz(mr, mi, -HP, 0);
    rowswap4(mr, mi, 1, 3);
    absorb_rz(mr, mi, wt[wb + 0], 1);
    absorb_ry(mr, mi, wt[wb + 1], 0);
    rowswap4(mr, mi, 2, 3);
    absorb_ry(mr, mi, wt[wb + 2], 0);
    rowswap4(mr, mi, 1, 3);
    absorb_rz(mr, mi, HP, 1);
    absorb_rz(mr, mi, -HP, 0);
    rowswap4(mr, mi, 1, 3);
    absorb_rz(mr, mi, wt[wb + 3], 1);
    absorb_ry(mr, mi, wt[wb + 4], 0);
    rowswap4(mr, mi, 2, 3);
    absorb_ry(mr, mi, wt[wb + 5], 0);
    if (nonadj) rowswap4(mr, mi, 1, 2);

    float* e = E4 + lane * 32;
#pragma unroll
    for (int r = 0; r < 4; r++)
#pragma unroll
      for (int c = 0; c < 4; c++) {
        e[(r * 4 + c) * 2]     = mr[r][c];
        e[(r * 4 + c) * 2 + 1] = mi[r][c];
      }
    meta[1 + 2 * lane] = myi;
    meta[2 + 2 * lane] = myj;
  }
}

// ---------------- K1: fused-gate basis-column simulation ----------------
__global__ __launch_bounds__(256) void build_u_kernel(const float* __restrict__ coup,
                                                      void* __restrict__ wsv) {
  const int* meta = (const int*)wsv;
  const float* Q1 = (const float*)((char*)wsv + 256);
  const float* E4 = (const float*)((char*)wsv + 512);
  unsigned char* Ub = (unsigned char*)wsv + 4096;

  const int c = blockIdx.x;
  const int tid = threadIdx.x;

  __shared__ float2 s[256];
  s[tid] = make_float2(tid == c ? 1.f : 0.f, 0.f);
  __syncthreads();

  for (int wi = 0; wi < 8; wi++) {
    const float* M = Q1 + wi * 8;
    int p = 7 - wi;
    float2 a0 = s[tid & ~(1 << p)];
    float2 a1 = s[tid | (1 << p)];
    int b = (tid >> p) & 1;
    float m0r = M[(b * 2 + 0) * 2], m0i = M[(b * 2 + 0) * 2 + 1];
    float m1r = M[(b * 2 + 1) * 2], m1i = M[(b * 2 + 1) * 2 + 1];
    float nr = m0r * a0.x - m0i * a0.y + m1r * a1.x - m1i * a1.y;
    float ni = m0r * a0.y + m0i * a0.x + m1r * a1.y + m1i * a1.x;
    __syncthreads();
    s[tid] = make_float2(nr, ni);
    __syncthreads();
  }

  for (int i = 0; i < 8; i++)
    for (int j = i + 1; j < 8; j++) {
      float t = coup[i * 8 + j];
      float ch = cosf(0.5f * t), sn = sinf(0.5f * t);
      int mask = (1 << (7 - i)) | (1 << (7 - j));
      float2 a = s[tid];
      float2 b = s[tid ^ mask];
      __syncthreads();
      s[tid] = make_float2(ch * a.x + sn * b.y, ch * a.y - sn * b.x);
      __syncthreads();
    }

  int ne = meta[0];
  for (int e = 0; e < ne; e++) {
    int i = meta[1 + 2 * e], j = meta[2 + 2 * e];
    int p1 = 7 - i, p2 = 7 - j;
    int m1 = 1 << p1, m2 = 1 << p2;
    int b = ((tid >> p1) & 1) * 2 + ((tid >> p2) & 1);
    int base = tid & ~(m1 | m2);
    float2 a0 = s[base];
    float2 a1 = s[base | m2];
    float2 a2 = s[base | m1];
    float2 a3 = s[base | m1 | m2];
    const float* M = E4 + e * 32 + b * 8;
    float nr = M[0] * a0.x - M[1] * a0.y + M[2] * a1.x - M[3] * a1.y
             + M[4] * a2.x - M[5] * a2.y + M[6] * a3.x - M[7] * a3.y;
    float ni = M[0] * a0.y + M[1] * a0.x + M[2] * a1.y + M[3] * a1.x
             + M[4] * a2.y + M[5] * a2.x + M[6] * a3.y + M[7] * a3.x;
    __syncthreads();
    s[tid] = make_float2(nr, ni);
    __syncthreads();
  }

  // write column c (logical k = c) into the pair-packed, slot-rotated chunk image
  {
    int ks = c >> 5, kc = c & 31;
    int sb = (kc >> 4) & 1, lg2 = (kc >> 2) & 3, ii = kc & 3;
    int p = (lg2 + tid) & 3;  // m>>1 == tid for both rows
    unsigned char* base = Ub + (size_t)ks * 32768 + (size_t)(2 * tid) * 64 + p * 16 + sb * 8 + ii * 2;
    *(unsigned short*)(base)      = f2bf(s[tid].x);
    *(unsigned short*)(base + 64) = f2bf(s[tid].y);
  }
}

// ---------------- K2: persistent blocks, U fragments in registers ----------------
// 256 blocks x 512 thr; wave wv owns M rows [wv*64, wv*64+64); A-frags 4x8 uint4 in regs.
// Per tile (64 batch rows): stage psi -> compute (256 _1k MFMA/wave) -> Z-reduce epilogue.
// LDS: psi bf16 [64][256] pair-packed, XOR-swizzled (32 KB); epilogue part[8][64][8] overlaps.
__global__ __launch_bounds__(512, 2) void gemm_persist(const float* __restrict__ x,
                                                       const void* __restrict__ wsv,
                                                       float* __restrict__ out) {
  const unsigned char* Ub = (const unsigned char*)wsv + 4096;
  __shared__ __align__(16) unsigned char smem[32768];

  const int tid = threadIdx.x;
  const int bid = blockIdx.x;
  const int wv = tid >> 6;
  const int lane = tid & 63;
  const int lm = lane & 15;
  const int lg = lane >> 4;

  // ---- load A fragments once: a_st[mf][ks] = 16B (both _1k halves) for row m, lane-group lg
  uint4 a_st[4][8];
#pragma unroll
  for (int mf = 0; mf < 4; mf++) {
    const int m = wv * 64 + mf * 16 + lm;
    const int p = (lg + (m >> 1)) & 3;
#pragma unroll
    for (int ks = 0; ks < 8; ks++)
      a_st[mf][ks] = *reinterpret_cast<const uint4*>(Ub + (size_t)ks * 32768 + (size_t)m * 64 + p * 16);
  }

  for (int t = 0; t < 4; t++) {
    const int tile = bid * 4 + t;

    // ---- stage psi: 64 rows, normalize, pair-packed bf16 into LDS ----
    {
      const int rl = tid >> 3;       // row 0..63
      const int seg = tid & 7;       // k-chunk 0..7 (32 floats)
      const float4* xs = (const float4*)(x + (size_t)(tile * 64 + rl) * 256 + seg * 32);
      float4 v[8];
      float ss = 0.f;
#pragma unroll
      for (int i = 0; i < 8; i++) {
        v[i] = xs[i];
        ss += v[i].x * v[i].x + v[i].y * v[i].y + v[i].z * v[i].z + v[i].w * v[i].w;
      }
      ss += __shfl_xor(ss, 1);
      ss += __shfl_xor(ss, 2);
      ss += __shfl_xor(ss, 4);
      float inv = 1.0f / sqrtf(ss);
      const float* vf = (const float*)v;
#pragma unroll
      for (int u = 0; u < 4; u++) {
        unsigned short h[8];
#pragma unroll
        for (int j = 0; j < 8; j++)   // j = 4*s + i  ->  k_local = 16*s + 4*u + i
          h[j] = f2bf(vf[16 * (j >> 2) + 4 * u + (j & 3)] * inv);
        uint4 pack;
        pack.x = (unsigned)h[0] | ((unsigned)h[1] << 16);
        pack.y = (unsigned)h[2] | ((unsigned)h[3] << 16);
        pack.z = (unsigned)h[4] | ((unsigned)h[5] << 16);
        pack.w = (unsigned)h[6] | ((unsigned)h[7] << 16);
        int byte = (rl * 512 + seg * 64 + u * 16) ^ ((rl & 7) << 4);
        *reinterpret_cast<uint4*>(&smem[byte]) = pack;
      }
    }
    __syncthreads();

    // ---- compute: 8 k32-chunks; B via one b128 per (nf, ks); A from registers ----
    f32x4 acc[4][4] = {};
#pragma unroll
    for (int ks = 0; ks < 8; ks++) {
      uint4 bq[4];
#pragma unroll
      for (int nf = 0; nf < 4; nf++) {
        const int n = nf * 16 + lm;
        int byte = (n * 512 + ks * 64 + lg * 16) ^ ((lm & 7) << 4);
        bq[nf] = *reinterpret_cast<const uint4*>(&smem[byte]);
      }
#pragma unroll
      for (int mf = 0; mf < 4; mf++) {
        const uint4 aq = a_st[mf][ks];
        const sh4 alo = __builtin_bit_cast(sh4, make_uint2(aq.x, aq.y));
        const sh4 ahi = __builtin_bit_cast(sh4, make_uint2(aq.z, aq.w));
#pragma unroll
        for (int nf = 0; nf < 4; nf++) {
          const sh4 blo = __builtin_bit_cast(sh4, make_uint2(bq[nf].x, bq[nf].y));
          const sh4 bhi = __builtin_bit_cast(sh4, make_uint2(bq[nf].z, bq[nf].w));
          acc[mf][nf] = __builtin_amdgcn_mfma_f32_16x16x16bf16_1k(alo, blo, acc[mf][nf], 0, 0, 0);
          acc[mf][nf] = __builtin_amdgcn_mfma_f32_16x16x16bf16_1k(ahi, bhi, acc[mf][nf], 0, 0, 0);
        }
      }
    }
    __syncthreads();   // all psi reads done (part region overlaps psi)

    // ---- epilogue: prob + signed Z-reduce (validated R5/R6/R7) ----
    float pq[4][8];
#pragma unroll
    for (int nf = 0; nf < 4; nf++) {
      float T = 0.f, S7 = 0.f, S4 = 0.f, S3 = 0.f;
#pragma unroll
      for (int mf = 0; mf < 4; mf++) {
        f32x4 a = acc[mf][nf];
        float p0 = a[0] * a[0] + a[1] * a[1];
        float p1 = a[2] * a[2] + a[3] * a[3];
        float sp = p0 + p1, d = p0 - p1;
        T += sp;
        S7 += d;
        S4 += (mf & 1) ? -sp : sp;
        S3 += (mf & 2) ? -sp : sp;
      }
      pq[nf][7] = S7;
      pq[nf][6] = (lg & 1) ? -T : T;
      pq[nf][5] = (lg & 2) ? -T : T;
      pq[nf][4] = S4;
      pq[nf][3] = S3;
      pq[nf][2] = (wv & 1) ? -T : T;
      pq[nf][1] = (wv & 2) ? -T : T;
      pq[nf][0] = (wv & 4) ? -T : T;
    }
#pragma unroll
    for (int nf = 0; nf < 4; nf++)
#pragma unroll
      for (int k = 0; k < 8; k++) {
        pq[nf][k] += __shfl_xor(pq[nf][k], 16);
        pq[nf][k] += __shfl_xor(pq[nf][k], 32);
      }

    float* part = (float*)smem;  // [8][64][8] = 16 KB
    if (lg == 0) {
#pragma unroll
      for (int nf = 0; nf < 4; nf++) {
        float* dst = part + (wv * 64 + nf * 16 + lm) * 8;
#pragma unroll
        for (int k = 0; k < 8; k++) dst[k] = pq[nf][k];
      }
    }
    __syncthreads();
    {
      int b = tid >> 3, q = tid & 7;
      float v2 = 0.f;
#pragma unroll
      for (int w2 = 0; w2 < 8; w2++) v2 += part[(w2 * 64 + b) * 8 + q];
      out[(size_t)(tile * 64 + b) * 8 + q] = v2;
    }
    __syncthreads();   // protect smem before next tile's staging
  }
}

extern "C" void kernel_launch(void* const* d_in, const int* in_sizes, int n_in,
                              void* d_out, int out_size, void* d_ws, size_t ws_size,
                              hipStream_t stream) {
  const float* x    = (const float*)d_in[0];
  const float* wt   = (const float*)d_in[1];
  const float* coup = (const float*)d_in[2];
  float* out = (float*)d_out;

  prep_kernel<<<1, 64, 0, stream>>>(wt, coup, d_ws);
  build_u_kernel<<<256, 256, 0, stream>>>(coup, d_ws);
  gemm_persist<<<256, 512, 0, stream>>>(x, d_ws, out);
}

// Round 9
// 64.435 us; speedup vs baseline: 1.1677x; 1.1677x over previous
//
#include <hip/hip_runtime.h>

#define HP 1.57079632679489662f

typedef float f32x4 __attribute__((ext_vector_type(4)));
typedef short sh4 __attribute__((ext_vector_type(4)));

__device__ __forceinline__ unsigned short f2bf(float f) {
  unsigned int u = __builtin_bit_cast(unsigned int, f);
  u += 0x7fffu + ((u >> 16) & 1u);
  return (unsigned short)(u >> 16);
}

// ---------------- helpers for 4x4 complex matrix absorption (G*M) ----------------
__device__ __forceinline__ void rowswap4(float (&mr)[4][4], float (&mi)[4][4], int a, int b) {
#pragma unroll
  for (int c = 0; c < 4; c++) {
    float tr = mr[a][c]; mr[a][c] = mr[b][c]; mr[b][c] = tr;
    float ti = mi[a][c]; mi[a][c] = mi[b][c]; mi[b][c] = ti;
  }
}

__device__ __forceinline__ void absorb_rz(float (&mr)[4][4], float (&mi)[4][4], float t, int bitpos) {
  float ch = cosf(0.5f * t), sh = sinf(0.5f * t);
#pragma unroll
  for (int r = 0; r < 4; r++) {
    float ph = ((r >> bitpos) & 1) ? sh : -sh;
#pragma unroll
    for (int c = 0; c < 4; c++) {
      float ar = mr[r][c], ai = mi[r][c];
      mr[r][c] = ch * ar - ph * ai;
      mi[r][c] = ch * ai + ph * ar;
    }
  }
}

__device__ __forceinline__ void absorb_ry(float (&mr)[4][4], float (&mi)[4][4], float t, int bitpos) {
  float ch = cosf(0.5f * t), sh = sinf(0.5f * t);
#pragma unroll
  for (int r = 0; r < 4; r++) {
    if ((r >> bitpos) & 1) continue;
    int rb = r | (1 << bitpos);
#pragma unroll
    for (int c = 0; c < 4; c++) {
      float ar = mr[r][c], ai = mi[r][c];
      float br = mr[rb][c], bi = mi[rb][c];
      mr[r][c]  = ch * ar - sh * br;  mi[r][c]  = ch * ai - sh * bi;
      mr[rb][c] = sh * ar + ch * br;  mi[rb][c] = sh * ai + ch * bi;
    }
  }
}

// ws layout:
//   int   meta[64]        @ 0    ; float Q1[8][8] @ 256 ; float E4[28][32] @ 512
//   bf16  Ub[8][512][32]  @ 4096 : chunk ks = k in [32ks,32ks+32); row m: 2r=Re,2r+1=Im
//         pair-packed: logical k = 32ks+16s+4lg+i at row-byte p*16 + 8s + 2i, p=(lg+(m>>1))&3

// ---------------- K0: edges (f64, exact numpy semantics) + gate fusion ----------------
__global__ __launch_bounds__(64) void prep_kernel(const float* __restrict__ wt,
                                                  const float* __restrict__ coup,
                                                  void* __restrict__ wsv) {
  const int lane = threadIdx.x;
  int* meta  = (int*)wsv;
  float* Q1  = (float*)((char*)wsv + 256);
  float* E4  = (float*)((char*)wsv + 512);

  double mn = 1e300, mx = -1e300;
  for (int k = 0; k < 64; k++) {
    double v = (double)coup[k];
    mn = v < mn ? v : mn;
    mx = v > mx ? v : mx;
  }
  int cnt = 0, myi = -1, myj = -1;
  for (int i = 0; i < 8; i++)
    for (int j = i + 1; j < 8; j++) {
      double cn = ((double)coup[i * 8 + j] - mn) / (mx - mn);
      if (cn > 0.5) {
        if (cnt == lane) { myi = i; myj = j; }
        cnt++;
      }
    }
  if (lane == 0) meta[0] = cnt;

  if (lane < 8) {
    float tx = wt[lane], ty = wt[8 + lane], tz = wt[16 + lane];
    float cx = cosf(0.5f * tx), sx = sinf(0.5f * tx);
    float cy = cosf(0.5f * ty), sy = sinf(0.5f * ty);
    float cz = cosf(0.5f * tz), sz = sinf(0.5f * tz);
    float m00r = cy * cx,  m00i = sy * sx;
    float m01r = -sy * cx, m01i = -cy * sx;
    float m10r = sy * cx,  m10i = -cy * sx;
    float m11r = cy * cx,  m11i = -sy * sx;
    float* q = Q1 + lane * 8;
    q[0] = cz * m00r + sz * m00i; q[1] = cz * m00i - sz * m00r;
    q[2] = cz * m01r + sz * m01i; q[3] = cz * m01i - sz * m01r;
    q[4] = cz * m10r - sz * m10i; q[5] = cz * m10i + sz * m10r;
    q[6] = cz * m11r - sz * m11i; q[7] = cz * m11i + sz * m11r;
  }

  if (lane < cnt && lane < 28) {
    float mr[4][4], mi[4][4];
#pragma unroll
    for (int r = 0; r < 4; r++)
#pragma unroll
      for (int c = 0; c < 4; c++) { mr[r][c] = (r == c) ? 1.f : 0.f; mi[r][c] = 0.f; }

    bool nonadj = (myj - myi) != 1;
    int wb = 24 + 6 * lane;

    if (nonadj) rowswap4(mr, mi, 1, 2);
    absorb_rz(mr, mi, -HP, 0);
    rowswap4(mr, mi, 1, 3);
    absorb_rz(mr, mi, wt[wb + 0], 1);
    absorb_ry(mr, mi, wt[wb + 1], 0);
    rowswap4(mr, mi, 2, 3);
    absorb_ry(mr, mi, wt[wb + 2], 0);
    rowswap4(mr, mi, 1, 3);
    absorb_rz(mr, mi, HP, 1);
    absorb_rz(mr, mi, -HP, 0);
    rowswap4(mr, mi, 1, 3);
    absorb_rz(mr, mi, wt[wb + 3], 1);
    absorb_ry(mr, mi, wt[wb + 4], 0);
    rowswap4(mr, mi, 2, 3);
    absorb_ry(mr, mi, wt[wb + 5], 0);
    if (nonadj) rowswap4(mr, mi, 1, 2);

    float* e = E4 + lane * 32;
#pragma unroll
    for (int r = 0; r < 4; r++)
#pragma unroll
      for (int c = 0; c < 4; c++) {
        e[(r * 4 + c) * 2]     = mr[r][c];
        e[(r * 4 + c) * 2 + 1] = mi[r][c];
      }
    meta[1 + 2 * lane] = myi;
    meta[2 + 2 * lane] = myj;
  }
}

// ---------------- K1: fused-gate basis-column simulation ----------------
__global__ __launch_bounds__(256) void build_u_kernel(const float* __restrict__ coup,
                                                      void* __restrict__ wsv) {
  const int* meta = (const int*)wsv;
  const float* Q1 = (const float*)((char*)wsv + 256);
  const float* E4 = (const float*)((char*)wsv + 512);
  unsigned char* Ub = (unsigned char*)wsv + 4096;

  const int c = blockIdx.x;
  const int tid = threadIdx.x;

  __shared__ float2 s[256];
  s[tid] = make_float2(tid == c ? 1.f : 0.f, 0.f);
  __syncthreads();

  for (int wi = 0; wi < 8; wi++) {
    const float* M = Q1 + wi * 8;
    int p = 7 - wi;
    float2 a0 = s[tid & ~(1 << p)];
    float2 a1 = s[tid | (1 << p)];
    int b = (tid >> p) & 1;
    float m0r = M[(b * 2 + 0) * 2], m0i = M[(b * 2 + 0) * 2 + 1];
    float m1r = M[(b * 2 + 1) * 2], m1i = M[(b * 2 + 1) * 2 + 1];
    float nr = m0r * a0.x - m0i * a0.y + m1r * a1.x - m1i * a1.y;
    float ni = m0r * a0.y + m0i * a0.x + m1r * a1.y + m1i * a1.x;
    __syncthreads();
    s[tid] = make_float2(nr, ni);
    __syncthreads();
  }

  for (int i = 0; i < 8; i++)
    for (int j = i + 1; j < 8; j++) {
      float t = coup[i * 8 + j];
      float ch = cosf(0.5f * t), sn = sinf(0.5f * t);
      int mask = (1 << (7 - i)) | (1 << (7 - j));
      float2 a = s[tid];
      float2 b = s[tid ^ mask];
      __syncthreads();
      s[tid] = make_float2(ch * a.x + sn * b.y, ch * a.y - sn * b.x);
      __syncthreads();
    }

  int ne = meta[0];
  for (int e = 0; e < ne; e++) {
    int i = meta[1 + 2 * e], j = meta[2 + 2 * e];
    int p1 = 7 - i, p2 = 7 - j;
    int m1 = 1 << p1, m2 = 1 << p2;
    int b = ((tid >> p1) & 1) * 2 + ((tid >> p2) & 1);
    int base = tid & ~(m1 | m2);
    float2 a0 = s[base];
    float2 a1 = s[base | m2];
    float2 a2 = s[base | m1];
    float2 a3 = s[base | m1 | m2];
    const float* M = E4 + e * 32 + b * 8;
    float nr = M[0] * a0.x - M[1] * a0.y + M[2] * a1.x - M[3] * a1.y
             + M[4] * a2.x - M[5] * a2.y + M[6] * a3.x - M[7] * a3.y;
    float ni = M[0] * a0.y + M[1] * a0.x + M[2] * a1.y + M[3] * a1.x
             + M[4] * a2.y + M[5] * a2.x + M[6] * a3.y + M[7] * a3.x;
    __syncthreads();
    s[tid] = make_float2(nr, ni);
    __syncthreads();
  }

  // write column c (logical k = c) into the pair-packed, slot-rotated chunk image
  {
    int ks = c >> 5, kc = c & 31;
    int sb = (kc >> 4) & 1, lg2 = (kc >> 2) & 3, ii = kc & 3;
    int p = (lg2 + tid) & 3;  // m>>1 == tid for both rows
    unsigned char* base = Ub + (size_t)ks * 32768 + (size_t)(2 * tid) * 64 + p * 16 + sb * 8 + ii * 2;
    *(unsigned short*)(base)      = f2bf(s[tid].x);
    *(unsigned short*)(base + 64) = f2bf(s[tid].y);
  }
}

// ---------------- K2: A from L2 into regs (2-deep pipeline), zero K-loop barriers -----
// 1024 blocks x 512 thr, 2 blocks/CU. psi bf16 [64][256] pair-packed XOR-swizzled in LDS.
#define MFMA_STEP(KS, AREG)                                                              \
  {                                                                                      \
    uint4 bq[4];                                                                         \
    _Pragma("unroll")                                                                    \
    for (int nf = 0; nf < 4; nf++) {                                                     \
      const int n = nf * 16 + lm;                                                        \
      int byte = (n * 512 + (KS) * 64 + lg * 16) ^ ((n & 7) << 4);                       \
      bq[nf] = *reinterpret_cast<const uint4*>(&smem[byte]);                             \
    }                                                                                    \
    _Pragma("unroll")                                                                    \
    for (int mf = 0; mf < 4; mf++) {                                                     \
      const sh4 alo = __builtin_bit_cast(sh4, make_uint2(AREG[mf].x, AREG[mf].y));       \
      const sh4 ahi = __builtin_bit_cast(sh4, make_uint2(AREG[mf].z, AREG[mf].w));       \
      _Pragma("unroll")                                                                  \
      for (int nf = 0; nf < 4; nf++) {                                                   \
        const sh4 blo = __builtin_bit_cast(sh4, make_uint2(bq[nf].x, bq[nf].y));         \
        const sh4 bhi = __builtin_bit_cast(sh4, make_uint2(bq[nf].z, bq[nf].w));         \
        acc[mf][nf] = __builtin_amdgcn_mfma_f32_16x16x16bf16_1k(alo, blo, acc[mf][nf], 0, 0, 0); \
        acc[mf][nf] = __builtin_amdgcn_mfma_f32_16x16x16bf16_1k(ahi, bhi, acc[mf][nf], 0, 0, 0); \
      }                                                                                  \
    }                                                                                    \
  }

__global__ __launch_bounds__(512, 4) void gemm_l2(const float* __restrict__ x,
                                                  const void* __restrict__ wsv,
                                                  float* __restrict__ out) {
  const unsigned char* Ub = (const unsigned char*)wsv + 4096;
  __shared__ __align__(16) unsigned char smem[32768];

  const int tid = threadIdx.x;
  const int tile = blockIdx.x;
  const int wv = tid >> 6;
  const int lane = tid & 63;
  const int lm = lane & 15;
  const int lg = lane >> 4;

  // ---- stage psi: 64 rows, normalize, pair-packed bf16 into LDS (proven R8) ----
  {
    const int rl = tid >> 3;
    const int seg = tid & 7;
    const float4* xs = (const float4*)(x + (size_t)(tile * 64 + rl) * 256 + seg * 32);
    float4 v[8];
    float ss = 0.f;
#pragma unroll
    for (int i = 0; i < 8; i++) {
      v[i] = xs[i];
      ss += v[i].x * v[i].x + v[i].y * v[i].y + v[i].z * v[i].z + v[i].w * v[i].w;
    }
    ss += __shfl_xor(ss, 1);
    ss += __shfl_xor(ss, 2);
    ss += __shfl_xor(ss, 4);
    float inv = 1.0f / sqrtf(ss);
    const float* vf = (const float*)v;
#pragma unroll
    for (int u = 0; u < 4; u++) {
      unsigned short h[8];
#pragma unroll
      for (int j = 0; j < 8; j++)
        h[j] = f2bf(vf[16 * (j >> 2) + 4 * u + (j & 3)] * inv);
      uint4 pack;
      pack.x = (unsigned)h[0] | ((unsigned)h[1] << 16);
      pack.y = (unsigned)h[2] | ((unsigned)h[3] << 16);
      pack.z = (unsigned)h[4] | ((unsigned)h[5] << 16);
      pack.w = (unsigned)h[6] | ((unsigned)h[7] << 16);
      int byte = (rl * 512 + seg * 64 + u * 16) ^ ((rl & 7) << 4);
      *reinterpret_cast<uint4*>(&smem[byte]) = pack;
    }
  }

  // A-fragment base addresses (per lane, per mf)
  const unsigned char* abase[4];
#pragma unroll
  for (int mf = 0; mf < 4; mf++) {
    const int m = wv * 64 + mf * 16 + lm;
    const int p = (lg + (m >> 1)) & 3;
    abase[mf] = Ub + (size_t)m * 64 + p * 16;
  }

  f32x4 acc[4][4] = {};
  uint4 aP[4], aQ[4];
#pragma unroll
  for (int mf = 0; mf < 4; mf++) aP[mf] = *reinterpret_cast<const uint4*>(abase[mf]);

  __syncthreads();  // psi staged

  // ---- K loop: 8 chunks, A double-buffered from L2, zero barriers ----
#pragma unroll
  for (int kk = 0; kk < 4; kk++) {
#pragma unroll
    for (int mf = 0; mf < 4; mf++)
      aQ[mf] = *reinterpret_cast<const uint4*>(abase[mf] + (size_t)(2 * kk + 1) * 32768);
    MFMA_STEP(2 * kk, aP);
    if (kk < 3) {
#pragma unroll
      for (int mf = 0; mf < 4; mf++)
        aP[mf] = *reinterpret_cast<const uint4*>(abase[mf] + (size_t)(2 * kk + 2) * 32768);
    }
    MFMA_STEP(2 * kk + 1, aQ);
  }
  __syncthreads();  // psi reads done (epilogue reuses smem)

  // ---- epilogue: prob + signed Z-reduce (validated R5-R8) ----
  float pq[4][8];
#pragma unroll
  for (int nf = 0; nf < 4; nf++) {
    float T = 0.f, S7 = 0.f, S4 = 0.f, S3 = 0.f;
#pragma unroll
    for (int mf = 0; mf < 4; mf++) {
      f32x4 a = acc[mf][nf];
      float p0 = a[0] * a[0] + a[1] * a[1];
      float p1 = a[2] * a[2] + a[3] * a[3];
      float sp = p0 + p1, d = p0 - p1;
      T += sp;
      S7 += d;
      S4 += (mf & 1) ? -sp : sp;
      S3 += (mf & 2) ? -sp : sp;
    }
    pq[nf][7] = S7;
    pq[nf][6] = (lg & 1) ? -T : T;
    pq[nf][5] = (lg & 2) ? -T : T;
    pq[nf][4] = S4;
    pq[nf][3] = S3;
    pq[nf][2] = (wv & 1) ? -T : T;
    pq[nf][1] = (wv & 2) ? -T : T;
    pq[nf][0] = (wv & 4) ? -T : T;
  }
#pragma unroll
  for (int nf = 0; nf < 4; nf++)
#pragma unroll
    for (int k = 0; k < 8; k++) {
      pq[nf][k] += __shfl_xor(pq[nf][k], 16);
      pq[nf][k] += __shfl_xor(pq[nf][k], 32);
    }

  float* part = (float*)smem;  // [8][64][8] = 16 KB
  if (lg == 0) {
#pragma unroll
    for (int nf = 0; nf < 4; nf++) {
      float* dst = part + (wv * 64 + nf * 16 + lm) * 8;
#pragma unroll
      for (int k = 0; k < 8; k++) dst[k] = pq[nf][k];
    }
  }
  __syncthreads();
  {
    int b = tid >> 3, q = tid & 7;
    float v2 = 0.f;
#pragma unroll
    for (int w2 = 0; w2 < 8; w2++) v2 += part[(w2 * 64 + b) * 8 + q];
    out[(size_t)(tile * 64 + b) * 8 + q] = v2;
  }
}

extern "C" void kernel_launch(void* const* d_in, const int* in_sizes, int n_in,
                              void* d_out, int out_size, void* d_ws, size_t ws_size,
                              hipStream_t stream) {
  const float* x    = (const float*)d_in[0];
  const float* wt   = (const float*)d_in[1];
  const float* coup = (const float*)d_in[2];
  float* out = (float*)d_out;

  prep_kernel<<<1, 64, 0, stream>>>(wt, coup, d_ws);
  build_u_kernel<<<256, 256, 0, stream>>>(coup, d_ws);
  gemm_l2<<<1024, 512, 0, stream>>>(x, d_ws, out);
}

// Round 10
// 58.574 us; speedup vs baseline: 1.2845x; 1.1001x over previous
//
#include <hip/hip_runtime.h>

#define HP 1.57079632679489662f

typedef float f32x4 __attribute__((ext_vector_type(4)));
typedef short sh4 __attribute__((ext_vector_type(4)));
typedef __bf16 bf16x8 __attribute__((ext_vector_type(8)));

__device__ __forceinline__ unsigned short f2bf(float f) {
  unsigned int u = __builtin_bit_cast(unsigned int, f);
  u += 0x7fffu + ((u >> 16) & 1u);
  return (unsigned short)(u >> 16);
}

// ---------------- helpers for 4x4 complex matrix absorption (G*M) ----------------
__device__ __forceinline__ void rowswap4(float (&mr)[4][4], float (&mi)[4][4], int a, int b) {
#pragma unroll
  for (int c = 0; c < 4; c++) {
    float tr = mr[a][c]; mr[a][c] = mr[b][c]; mr[b][c] = tr;
    float ti = mi[a][c]; mi[a][c] = mi[b][c]; mi[b][c] = ti;
  }
}

__device__ __forceinline__ void absorb_rz(float (&mr)[4][4], float (&mi)[4][4], float t, int bitpos) {
  float ch = cosf(0.5f * t), sh = sinf(0.5f * t);
#pragma unroll
  for (int r = 0; r < 4; r++) {
    float ph = ((r >> bitpos) & 1) ? sh : -sh;
#pragma unroll
    for (int c = 0; c < 4; c++) {
      float ar = mr[r][c], ai = mi[r][c];
      mr[r][c] = ch * ar - ph * ai;
      mi[r][c] = ch * ai + ph * ar;
    }
  }
}

__device__ __forceinline__ void absorb_ry(float (&mr)[4][4], float (&mi)[4][4], float t, int bitpos) {
  float ch = cosf(0.5f * t), sh = sinf(0.5f * t);
#pragma unroll
  for (int r = 0; r < 4; r++) {
    if ((r >> bitpos) & 1) continue;
    int rb = r | (1 << bitpos);
#pragma unroll
    for (int c = 0; c < 4; c++) {
      float ar = mr[r][c], ai = mi[r][c];
      float br = mr[rb][c], bi = mi[rb][c];
      mr[r][c]  = ch * ar - sh * br;  mi[r][c]  = ch * ai - sh * bi;
      mr[rb][c] = sh * ar + ch * br;  mi[rb][c] = sh * ai + ch * bi;
    }
  }
}

// ws layout:
//   bf16 Ub[8][512][32] @ 4096 : chunk ks = k in [32ks,32ks+32); row m: 2r=Re,2r+1=Im
//        pair-packed: logical k = 32ks+16s+4g+i at row-byte p*16 + 8s + 2i, p=(g+(m>>1))&3

// ---------------- K1: inline prep + fused-gate basis-column simulation ----------------
__global__ __launch_bounds__(256) void build_u_kernel(const float* __restrict__ wt,
                                                      const float* __restrict__ coup,
                                                      void* __restrict__ wsv) {
  unsigned char* Ub = (unsigned char*)wsv + 4096;
  const int c = blockIdx.x;
  const int tid = threadIdx.x;

  __shared__ float2 s[256];
  __shared__ float Q1s[64];      // 8 wires x (2x2 complex)
  __shared__ float E4s[28 * 32]; // 28 edges x (4x4 complex)
  __shared__ int metas[57];      // [0]=ne, then (i,j) pairs

  // ---- inline prep (exact numpy f64 edge semantics; redundant across threads) ----
  {
    double mn = 1e300, mx = -1e300;
    for (int k = 0; k < 64; k++) {
      double v = (double)coup[k];
      mn = v < mn ? v : mn;
      mx = v > mx ? v : mx;
    }
    int cnt = 0, myi = -1, myj = -1;
    for (int i = 0; i < 8; i++)
      for (int j = i + 1; j < 8; j++) {
        double cn = ((double)coup[i * 8 + j] - mn) / (mx - mn);
        if (cn > 0.5) {
          if (cnt == tid) { myi = i; myj = j; }
          cnt++;
        }
      }
    if (tid == 0) metas[0] = cnt;

    if (tid < 8) {
      float tx = wt[tid], ty = wt[8 + tid], tz = wt[16 + tid];
      float cx = cosf(0.5f * tx), sx = sinf(0.5f * tx);
      float cy = cosf(0.5f * ty), sy = sinf(0.5f * ty);
      float cz = cosf(0.5f * tz), sz = sinf(0.5f * tz);
      float m00r = cy * cx,  m00i = sy * sx;
      float m01r = -sy * cx, m01i = -cy * sx;
      float m10r = sy * cx,  m10i = -cy * sx;
      float m11r = cy * cx,  m11i = -sy * sx;
      float* q = Q1s + tid * 8;
      q[0] = cz * m00r + sz * m00i; q[1] = cz * m00i - sz * m00r;
      q[2] = cz * m01r + sz * m01i; q[3] = cz * m01i - sz * m01r;
      q[4] = cz * m10r - sz * m10i; q[5] = cz * m10i + sz * m10r;
      q[6] = cz * m11r - sz * m11i; q[7] = cz * m11i + sz * m11r;
    }

    if (tid < cnt && tid < 28) {
      float mr[4][4], mi[4][4];
#pragma unroll
      for (int r = 0; r < 4; r++)
#pragma unroll
        for (int cc = 0; cc < 4; cc++) { mr[r][cc] = (r == cc) ? 1.f : 0.f; mi[r][cc] = 0.f; }

      bool nonadj = (myj - myi) != 1;
      int wb = 24 + 6 * tid;

      if (nonadj) rowswap4(mr, mi, 1, 2);
      absorb_rz(mr, mi, -HP, 0);
      rowswap4(mr, mi, 1, 3);
      absorb_rz(mr, mi, wt[wb + 0], 1);
      absorb_ry(mr, mi, wt[wb + 1], 0);
      rowswap4(mr, mi, 2, 3);
      absorb_ry(mr, mi, wt[wb + 2], 0);
      rowswap4(mr, mi, 1, 3);
      absorb_rz(mr, mi, HP, 1);
      absorb_rz(mr, mi, -HP, 0);
      rowswap4(mr, mi, 1, 3);
      absorb_rz(mr, mi, wt[wb + 3], 1);
      absorb_ry(mr, mi, wt[wb + 4], 0);
      rowswap4(mr, mi, 2, 3);
      absorb_ry(mr, mi, wt[wb + 5], 0);
      if (nonadj) rowswap4(mr, mi, 1, 2);

      float* e = E4s + tid * 32;
#pragma unroll
      for (int r = 0; r < 4; r++)
#pragma unroll
        for (int cc = 0; cc < 4; cc++) {
          e[(r * 4 + cc) * 2]     = mr[r][cc];
          e[(r * 4 + cc) * 2 + 1] = mi[r][cc];
        }
      metas[1 + 2 * tid] = myi;
      metas[2 + 2 * tid] = myj;
    }
  }

  s[tid] = make_float2(tid == c ? 1.f : 0.f, 0.f);
  __syncthreads();

  // ---- fused 1q per wire (wire w -> amplitude bit 7-w) ----
  for (int wi = 0; wi < 8; wi++) {
    const float* M = Q1s + wi * 8;
    int p = 7 - wi;
    float2 a0 = s[tid & ~(1 << p)];
    float2 a1 = s[tid | (1 << p)];
    int b = (tid >> p) & 1;
    float m0r = M[(b * 2 + 0) * 2], m0i = M[(b * 2 + 0) * 2 + 1];
    float m1r = M[(b * 2 + 1) * 2], m1i = M[(b * 2 + 1) * 2 + 1];
    float nr = m0r * a0.x - m0i * a0.y + m1r * a1.x - m1i * a1.y;
    float ni = m0r * a0.y + m0i * a0.x + m1r * a1.y + m1i * a1.x;
    __syncthreads();
    s[tid] = make_float2(nr, ni);
    __syncthreads();
  }

  // ---- IsingXX on all pairs ----
  for (int i = 0; i < 8; i++)
    for (int j = i + 1; j < 8; j++) {
      float t = coup[i * 8 + j];
      float ch = cosf(0.5f * t), sn = sinf(0.5f * t);
      int mask = (1 << (7 - i)) | (1 << (7 - j));
      float2 a = s[tid];
      float2 b = s[tid ^ mask];
      __syncthreads();
      s[tid] = make_float2(ch * a.x + sn * b.y, ch * a.y - sn * b.x);
      __syncthreads();
    }

  // ---- fused edges ----
  int ne = metas[0];
  for (int e = 0; e < ne; e++) {
    int i = metas[1 + 2 * e], j = metas[2 + 2 * e];
    int p1 = 7 - i, p2 = 7 - j;
    int m1 = 1 << p1, m2 = 1 << p2;
    int b = ((tid >> p1) & 1) * 2 + ((tid >> p2) & 1);
    int base = tid & ~(m1 | m2);
    float2 a0 = s[base];
    float2 a1 = s[base | m2];
    float2 a2 = s[base | m1];
    float2 a3 = s[base | m1 | m2];
    const float* M = E4s + e * 32 + b * 8;
    float nr = M[0] * a0.x - M[1] * a0.y + M[2] * a1.x - M[3] * a1.y
             + M[4] * a2.x - M[5] * a2.y + M[6] * a3.x - M[7] * a3.y;
    float ni = M[0] * a0.y + M[1] * a0.x + M[2] * a1.y + M[3] * a1.x
             + M[4] * a2.y + M[5] * a2.x + M[6] * a3.y + M[7] * a3.x;
    __syncthreads();
    s[tid] = make_float2(nr, ni);
    __syncthreads();
  }

  // ---- write column c into the pair-packed, slot-rotated chunk image (proven R9) ----
  {
    int ks = c >> 5, kc = c & 31;
    int sb = (kc >> 4) & 1, lg2 = (kc >> 2) & 3, ii = kc & 3;
    int p = (lg2 + tid) & 3;  // m>>1 == tid for both rows
    unsigned char* base = Ub + (size_t)ks * 32768 + (size_t)(2 * tid) * 64 + p * 16 + sb * 8 + ii * 2;
    *(unsigned short*)(base)      = f2bf(s[tid].x);
    *(unsigned short*)(base + 64) = f2bf(s[tid].y);
  }
}

// ---------------- K2: A from L2 into regs (2-deep pipeline), zero K-loop barriers -----
// 1024 blocks x 512 thr, 2 blocks/CU. psi bf16 [64][256] pair-packed XOR-swizzled in LDS.
#define MFMA_STEP(KS, AREG)                                                              \
  {                                                                                      \
    uint4 bq[4];                                                                         \
    _Pragma("unroll")                                                                    \
    for (int nf = 0; nf < 4; nf++) {                                                     \
      const int n = nf * 16 + lm;                                                        \
      int byte = (n * 512 + (KS) * 64 + lg * 16) ^ ((n & 7) << 4);                       \
      bq[nf] = *reinterpret_cast<const uint4*>(&smem[byte]);                             \
    }                                                                                    \
    __builtin_amdgcn_s_setprio(1);                                                       \
    _Pragma("unroll")                                                                    \
    for (int mf = 0; mf < 4; mf++) {                                                     \
      const sh4 alo = __builtin_bit_cast(sh4, make_uint2(AREG[mf].x, AREG[mf].y));       \
      const sh4 ahi = __builtin_bit_cast(sh4, make_uint2(AREG[mf].z, AREG[mf].w));       \
      _Pragma("unroll")                                                                  \
      for (int nf = 0; nf < 4; nf++) {                                                   \
        const sh4 blo = __builtin_bit_cast(sh4, make_uint2(bq[nf].x, bq[nf].y));         \
        const sh4 bhi = __builtin_bit_cast(sh4, make_uint2(bq[nf].z, bq[nf].w));         \
        acc[mf][nf] = __builtin_amdgcn_mfma_f32_16x16x16bf16_1k(alo, blo, acc[mf][nf], 0, 0, 0); \
        acc[mf][nf] = __builtin_amdgcn_mfma_f32_16x16x16bf16_1k(ahi, bhi, acc[mf][nf], 0, 0, 0); \
      }                                                                                  \
    }                                                                                    \
    __builtin_amdgcn_s_setprio(0);                                                       \
  }

__global__ __launch_bounds__(512, 4) void gemm_l2(const float* __restrict__ x,
                                                  const void* __restrict__ wsv,
                                                  float* __restrict__ out) {
  const unsigned char* Ub = (const unsigned char*)wsv + 4096;
  __shared__ __align__(16) unsigned char smem[32768];

  const int tid = threadIdx.x;
  const int tile = blockIdx.x;
  const int wv = tid >> 6;
  const int lane = tid & 63;
  const int lm = lane & 15;
  const int lg = lane >> 4;

  // ---- hoisted: A-fragment bases + first-chunk A loads (issue before stage VALU) ----
  const unsigned char* abase[4];
#pragma unroll
  for (int mf = 0; mf < 4; mf++) {
    const int m = wv * 64 + mf * 16 + lm;
    const int p = (lg + (m >> 1)) & 3;
    abase[mf] = Ub + (size_t)m * 64 + p * 16;
  }
  uint4 aP[4], aQ[4];
#pragma unroll
  for (int mf = 0; mf < 4; mf++) aP[mf] = *reinterpret_cast<const uint4*>(abase[mf]);

  // ---- stage psi: 64 rows, normalize, pair-packed bf16 into LDS (native cvt) ----
  {
    const int rl = tid >> 3;
    const int seg = tid & 7;
    const float4* xs = (const float4*)(x + (size_t)(tile * 64 + rl) * 256 + seg * 32);
    float4 v[8];
    float ss = 0.f;
#pragma unroll
    for (int i = 0; i < 8; i++) {
      v[i] = xs[i];
      ss += v[i].x * v[i].x + v[i].y * v[i].y + v[i].z * v[i].z + v[i].w * v[i].w;
    }
    ss += __shfl_xor(ss, 1);
    ss += __shfl_xor(ss, 2);
    ss += __shfl_xor(ss, 4);
    float inv = 1.0f / sqrtf(ss);
    const float* vf = (const float*)v;
#pragma unroll
    for (int u = 0; u < 4; u++) {
      bf16x8 w;
#pragma unroll
      for (int j = 0; j < 8; j++)
        w[j] = (__bf16)(vf[16 * (j >> 2) + 4 * u + (j & 3)] * inv);
      uint4 pack = __builtin_bit_cast(uint4, w);
      int byte = (rl * 512 + seg * 64 + u * 16) ^ ((rl & 7) << 4);
      *reinterpret_cast<uint4*>(&smem[byte]) = pack;
    }
  }

  f32x4 acc[4][4] = {};
  __syncthreads();  // psi staged

  // ---- K loop: 8 chunks, A double-buffered from L2, zero barriers ----
#pragma unroll
  for (int kk = 0; kk < 4; kk++) {
#pragma unroll
    for (int mf = 0; mf < 4; mf++)
      aQ[mf] = *reinterpret_cast<const uint4*>(abase[mf] + (size_t)(2 * kk + 1) * 32768);
    MFMA_STEP(2 * kk, aP);
    if (kk < 3) {
#pragma unroll
      for (int mf = 0; mf < 4; mf++)
        aP[mf] = *reinterpret_cast<const uint4*>(abase[mf] + (size_t)(2 * kk + 2) * 32768);
    }
    MFMA_STEP(2 * kk + 1, aQ);
  }
  __syncthreads();  // psi reads done (epilogue reuses smem)

  // ---- epilogue: prob + signed Z-reduce (validated R5-R9) ----
  float pq[4][8];
#pragma unroll
  for (int nf = 0; nf < 4; nf++) {
    float T = 0.f, S7 = 0.f, S4 = 0.f, S3 = 0.f;
#pragma unroll
    for (int mf = 0; mf < 4; mf++) {
      f32x4 a = acc[mf][nf];
      float p0 = a[0] * a[0] + a[1] * a[1];
      float p1 = a[2] * a[2] + a[3] * a[3];
      float sp = p0 + p1, d = p0 - p1;
      T += sp;
      S7 += d;
      S4 += (mf & 1) ? -sp : sp;
      S3 += (mf & 2) ? -sp : sp;
    }
    pq[nf][7] = S7;
    pq[nf][6] = (lg & 1) ? -T : T;
    pq[nf][5] = (lg & 2) ? -T : T;
    pq[nf][4] = S4;
    pq[nf][3] = S3;
    pq[nf][2] = (wv & 1) ? -T : T;
    pq[nf][1] = (wv & 2) ? -T : T;
    pq[nf][0] = (wv & 4) ? -T : T;
  }
#pragma unroll
  for (int nf = 0; nf < 4; nf++)
#pragma unroll
    for (int k = 0; k < 8; k++) {
      pq[nf][k] += __shfl_xor(pq[nf][k], 16);
      pq[nf][k] += __shfl_xor(pq[nf][k], 32);
    }

  float* part = (float*)smem;  // [8][64][8] = 16 KB
  if (lg == 0) {
#pragma unroll
    for (int nf = 0; nf < 4; nf++) {
      float* dst = part + (wv * 64 + nf * 16 + lm) * 8;
#pragma unroll
      for (int k = 0; k < 8; k++) dst[k] = pq[nf][k];
    }
  }
  __syncthreads();
  {
    int b = tid >> 3, q = tid & 7;
    float v2 = 0.f;
#pragma unroll
    for (int w2 = 0; w2 < 8; w2++) v2 += part[(w2 * 64 + b) * 8 + q];
    out[(size_t)(tile * 64 + b) * 8 + q] = v2;
  }
}

extern "C" void kernel_launch(void* const* d_in, const int* in_sizes, int n_in,
                              void* d_out, int out_size, void* d_ws, size_t ws_size,
                              hipStream_t stream) {
  const float* x    = (const float*)d_in[0];
  const float* wt   = (const float*)d_in[1];
  const float* coup = (const float*)d_in[2];
  float* out = (float*)d_out;

  build_u_kernel<<<256, 256, 0, stream>>>(wt, coup, d_ws);
  gemm_l2<<<1024, 512, 0, stream>>>(x, d_ws, out);
}